// Round 5
// baseline (1850.667 us; speedup 1.0000x reference)
//
#include <hip/hip_runtime.h>
#include <hip/hip_bf16.h>

#define NA 8192
#define NB 8192
#define NE 32768
#define NC 8
#define CHW 2048   // 8*16*16
#define WPB 4      // waves per block
#define NBLK 768   // grid: 3 blocks/CU * 256 CU -> all resident
#define NWAVES (NBLK * WPB)          // 3072; 2048 %% 4 == 0 -> equal iters per block
#define ROWP 20    // padded row stride in words (odd*4 -> bank spread, 16B-aligned)
#define EFW (NC * 16 * ROWP)         // 2560 words (10240 B) per wave

typedef float f4 __attribute__((ext_vector_type(4)));

// zero h region (float4) + cnt region (int4)
__global__ __launch_bounds__(256) void zero_kernel(
    float4* __restrict__ h, size_t nh4, int4* __restrict__ cnt, size_t nc4)
{
    const float4 z4 = make_float4(0.f, 0.f, 0.f, 0.f);
    const int4 zi4 = make_int4(0, 0, 0, 0);
    size_t stride = (size_t)gridDim.x * blockDim.x;
    for (size_t i = (size_t)blockIdx.x * blockDim.x + threadIdx.x; i < nh4; i += stride)
        h[i] = z4;
    for (size_t i = (size_t)blockIdx.x * blockDim.x + threadIdx.x; i < nc4; i += stride)
        cnt[i] = zi4;
}

__global__ __launch_bounds__(256) void hist_kernel(
    const int* __restrict__ dst, int* __restrict__ cnt, int n) {
    int i = blockIdx.x * 256 + threadIdx.x;
    if (i < n) atomicAdd(&cnt[dst[i]], 1);
}

// One WAVE per edge (loops over ~10 edges). Thread owns 4 x-positions of one
// row: y = lane>>2, x = xb..xb+3, all 8 output channels -> 32 accumulators.
// Patch reads: 3 rows x (b128 + 2 b32) per ci  => ~72 DS instr per edge-wave
// (vs ~500 in the per-position layout -> LDS pipe no longer oversubscribed).
// Weights read from global per (ci,co) as dwordx4 (2.6KB, L1-resident broadcast).
__global__ __launch_bounds__(256, 3) void conv_kernel(
    const float* __restrict__ feat_src,   // [Nsrc, 2048]
    const float* __restrict__ feat_dst,   // [Ndst, 2048]
    const float* __restrict__ Wc,         // [8,8,3,3] OIHW
    const float* __restrict__ bias,       // [8]
    const int*   __restrict__ src_idx,    // [E]
    const int*   __restrict__ dst_idx,    // [E]
    const int*   __restrict__ cnt,        // [Ndst] in-degree
    float*       __restrict__ Wh_out,     // [E, 2048]
    float*       __restrict__ h_acc)      // [Ndst, 2048] pre-zeroed
{
    __shared__ float lds[WPB * EFW];      // 40 KB/block -> 3 blocks/CU

    const int tid  = threadIdx.x;
    const int lane = tid & 63;
    const int widx = tid >> 6;
    float* ef = &lds[widx * EFW];         // wave-private [8][16][ROWP]

    const int gwave = blockIdx.x * WPB + widx;
    const int y  = lane >> 2;             // 0..15
    const int xb = (lane & 3) * 4;        // 0,4,8,12

    float bco[NC];
    #pragma unroll
    for (int co = 0; co < NC; ++co) bco[co] = bias[co];

    for (int e = gwave; e < NE; e += NWAVES) {
        const int s = src_idx[e];
        const int d = dst_idx[e];

        __syncthreads();   // protect prev-iter LDS reads from this iter's writes

        // ---- stage ef = u + v into wave-private LDS [8][16][ROWP] ----
        {
            const float4* up = (const float4*)(feat_src + (size_t)s * CHW);
            const float4* vp = (const float4*)(feat_dst + (size_t)d * CHW);
            #pragma unroll
            for (int k = 0; k < 8; ++k) {
                int i4 = lane + 64 * k;            // 0..511
                float4 u = up[i4];
                float4 v = vp[i4];
                int c  = i4 >> 6;
                int yy = (i4 >> 2) & 15;
                int xx = (i4 & 3) * 4;
                f4 efv = { u.x + v.x, u.y + v.y, u.z + v.z, u.w + v.w };
                *(f4*)&ef[c * (16 * ROWP) + yy * ROWP + xx] = efv;
            }
        }
        __syncthreads();   // writes visible before reads

        // ---- conv3x3, all 8 co, 4 x-positions per thread ----
        float wh[4][NC];
        #pragma unroll
        for (int i = 0; i < 4; ++i)
            #pragma unroll
            for (int co = 0; co < NC; ++co) wh[i][co] = bco[co];

        #pragma unroll
        for (int ci = 0; ci < NC; ++ci) {
            // 6-wide window, 3 rows, boundary-zeroed
            float win[3][6];
            #pragma unroll
            for (int r = 0; r < 3; ++r) {
                int yy = y + r - 1;
                int yc = yy < 0 ? 0 : (yy > 15 ? 15 : yy);
                const float* rowp = &ef[ci * (16 * ROWP) + yc * ROWP];
                f4 mid = *(const f4*)&rowp[xb];
                float lf = rowp[xb > 0 ? xb - 1 : 0];
                float rt = rowp[xb < 12 ? xb + 4 : 15];
                const bool rowOK = (yy >= 0) && (yy <= 15);
                win[r][0] = (rowOK && xb > 0)  ? lf    : 0.f;
                win[r][1] = rowOK              ? mid.x : 0.f;
                win[r][2] = rowOK              ? mid.y : 0.f;
                win[r][3] = rowOK              ? mid.z : 0.f;
                win[r][4] = rowOK              ? mid.w : 0.f;
                win[r][5] = (rowOK && xb < 12) ? rt    : 0.f;
            }
            // weights for this ci: 9 floats per co, from global (L1 broadcast)
            #pragma unroll
            for (int co = 0; co < NC; ++co) {
                const float* wp = Wc + (size_t)co * 72 + (size_t)ci * 9;
                float w[9];
                #pragma unroll
                for (int t = 0; t < 9; ++t) w[t] = wp[t];
                #pragma unroll
                for (int r = 0; r < 3; ++r)
                    #pragma unroll
                    for (int i = 0; i < 4; ++i)
                        #pragma unroll
                        for (int kx = 0; kx < 3; ++kx)
                            wh[i][co] = fmaf(win[r][i + kx], w[r * 3 + kx], wh[i][co]);
            }
        }

        // ---- epilogue: Wh nontemporal f4 store; m=(u+Wh)/deg atomics ----
        const float inv = 1.0f / (float)cnt[d];
        float*       whp = Wh_out + (size_t)e * CHW;
        const float* u2  = feat_src + (size_t)s * CHW;
        float*       hp  = h_acc + (size_t)d * CHW;
        #pragma unroll
        for (int co = 0; co < NC; ++co) {
            const int o = co * 256 + y * 16 + xb;
            f4 w4 = { wh[0][co], wh[1][co], wh[2][co], wh[3][co] };
            __builtin_nontemporal_store(w4, (f4*)&whp[o]);
            f4 u4 = *(const f4*)&u2[o];
            atomicAdd(&hp[o + 0], (u4.x + w4.x) * inv);
            atomicAdd(&hp[o + 1], (u4.y + w4.y) * inv);
            atomicAdd(&hp[o + 2], (u4.z + w4.z) * inv);
            atomicAdd(&hp[o + 3], (u4.w + w4.w) * inv);
        }
    }
}

extern "C" void kernel_launch(void* const* d_in, const int* in_sizes, int n_in,
                              void* d_out, int out_size, void* d_ws, size_t ws_size,
                              hipStream_t stream) {
    const float* feat_a = (const float*)d_in[0];
    const float* feat_b = (const float*)d_in[1];
    const float* W_e1   = (const float*)d_in[2];
    const float* b_e1   = (const float*)d_in[3];
    const float* W_e2   = (const float*)d_in[4];
    const float* b_e2   = (const float*)d_in[5];
    const int*   src_e1 = (const int*)d_in[6];
    const int*   dst_e1 = (const int*)d_in[7];
    const int*   src_e2 = (const int*)d_in[8];
    const int*   dst_e2 = (const int*)d_in[9];

    float* out = (float*)d_out;
    float* h_a = out;                                  // [NA, 2048]
    float* h_b = out + (size_t)NA * CHW;               // [NB, 2048]
    float* Wh1 = out + (size_t)(NA + NB) * CHW;        // [E, 2048]
    float* Wh2 = Wh1 + (size_t)NE * CHW;               // [E, 2048]

    int* cnt_a = (int*)d_ws;        // [NA] in-degree under etype2 (dst in a)
    int* cnt_b = cnt_a + NA;        // [NB] in-degree under etype1 (dst in b)

    // zero h accumulators + counts
    size_t nh4 = (size_t)(NA + NB) * CHW / 4;
    size_t nc4 = (size_t)(NA + NB) / 4;
    zero_kernel<<<2048, 256, 0, stream>>>((float4*)h_a, nh4, (int4*)d_ws, nc4);

    // in-degree histograms
    hist_kernel<<<(NE + 255) / 256, 256, 0, stream>>>(dst_e1, cnt_b, NE);
    hist_kernel<<<(NE + 255) / 256, 256, 0, stream>>>(dst_e2, cnt_a, NE);

    // etype e1: a -> b   (writes Wh1, accumulates mean into h_b)
    conv_kernel<<<NBLK, 256, 0, stream>>>(feat_a, feat_b, W_e1, b_e1,
                                          src_e1, dst_e1, cnt_b, Wh1, h_b);
    // etype e2: b -> a   (writes Wh2, accumulates mean into h_a)
    conv_kernel<<<NBLK, 256, 0, stream>>>(feat_b, feat_a, W_e2, b_e2,
                                          src_e2, dst_e2, cnt_a, Wh2, h_a);
}

// Round 7
// 1717.919 us; speedup vs baseline: 1.0773x; 1.0773x over previous
//
#include <hip/hip_runtime.h>
#include <hip/hip_bf16.h>

#define NA 8192
#define NB 8192
#define NE 32768
#define NC 8
#define CHW 2048        // 8*16*16
#define EPB 16          // edges per block (serial, prefetched)
#define NBLK (NE / EPB) // 2048 blocks
#define ROWW 20         // words per padded row (2-way-bank-conflict stride, 16B-aligned cols)
#define PLANE (18 * ROWW)           // 360 words per ci plane (rows 0,17 = zero pads)
#define TILEW (NC * PLANE + 4)      // +4: right-halo of last row aliases past end

typedef float f4 __attribute__((ext_vector_type(4)));
typedef int   i4v __attribute__((ext_vector_type(4)));

// zero h region (f4) + cnt region (i4v)
__global__ __launch_bounds__(256) void zero_kernel(
    f4* __restrict__ h, size_t nh4, i4v* __restrict__ cnt, size_t nc4)
{
    const f4 z4 = {0.f, 0.f, 0.f, 0.f};
    const i4v zi4 = {0, 0, 0, 0};
    size_t stride = (size_t)gridDim.x * blockDim.x;
    for (size_t i = (size_t)blockIdx.x * blockDim.x + threadIdx.x; i < nh4; i += stride)
        h[i] = z4;
    for (size_t i = (size_t)blockIdx.x * blockDim.x + threadIdx.x; i < nc4; i += stride)
        cnt[i] = zi4;
}

__global__ __launch_bounds__(256) void hist_kernel(
    const int* __restrict__ dst, int* __restrict__ cnt, int n) {
    int i = blockIdx.x * 256 + threadIdx.x;
    if (i < n) atomicAdd(&cnt[dst[i]], 1);
}

// Block = 256 threads, processes EPB edges serially (prefetch next edge's u,v).
// Thread owns: 1 output channel (co = tid>>5), a 2x4 spatial block
//   (y0 = 2*((tid&31)>>2), x = 4*((tid&31)&3) .. +4)  -> 8 outputs, 72 weights.
// LDS tile: ef[ci][18][20], rows 0/17 + col 0..3 zeroed ONCE; per-edge writes
// touch rows 1..16, cols 4..19 only. Right-halo read (col 20) aliases the next
// row's left zero pad -> branch-free conv, all offsets compile-time.
__global__ __launch_bounds__(256, 4) void conv_kernel(
    const float* __restrict__ feat_src,   // [Nsrc, 2048]
    const float* __restrict__ feat_dst,   // [Ndst, 2048]
    const float* __restrict__ Wc,         // [8,8,3,3] OIHW
    const float* __restrict__ bias,       // [8]
    const int*   __restrict__ src_idx,    // [E]
    const int*   __restrict__ dst_idx,    // [E]
    const int*   __restrict__ cnt,        // [Ndst] in-degree
    float*       __restrict__ Wh_out,     // [E, 2048]
    float*       __restrict__ h_acc)      // [Ndst, 2048] pre-zeroed
{
    __shared__ float s_ef[TILEW];         // 11.5 KB
    __shared__ float s_w[NC * NC * 9];    // [ci*8+co][9], 2.25 KB

    const int tid = threadIdx.x;
    const int co  = tid >> 5;             // 0..7
    const int r   = tid & 31;
    const int y0  = (r >> 2) << 1;        // 0,2,..,14
    const int xg  = (r & 3) << 2;         // 0,4,8,12

    // zero whole tile once (interior gets overwritten every edge)
    for (int i = tid; i < TILEW; i += 256) s_ef[i] = 0.0f;
    // repack weights [co][ci][t] -> s_w[(ci*8+co)*9 + t]
    for (int i = tid; i < NC * NC * 9; i += 256) {
        int co_ = i / 72, rem = i % 72, ci_ = rem / 9, t = rem % 9;
        s_w[(ci_ * NC + co_) * 9 + t] = Wc[i];
    }
    const float bco = bias[co];

    // per-thread constant addresses
    //   staging: f4 slots i4 = tid and tid+256
    const int i4a = tid, i4b = tid + 256;
    const int sa = (i4a >> 6) * PLANE + (((i4a >> 2) & 15) + 1) * ROWW + (i4a & 3) * 4 + 4;
    const int sb = (i4b >> 6) * PLANE + (((i4b >> 2) & 15) + 1) * ROWW + (i4b & 3) * 4 + 4;
    //   window base: padded rows y0..y0+3, col group xg
    const int wbase = y0 * ROWW + xg;
    //   weight base for this co
    const int wgt0 = co * 9;
    //   output offsets (row y0 and y0+1 of plane co)
    const int offA = co * 256 + y0 * 16 + xg;
    const int offB = offA + 16;

    const int e0 = blockIdx.x * EPB;

    // ---- prologue: load + stage edge e0 ----
    int sNxt = src_idx[e0];
    int dNxt = dst_idx[e0];
    f4 pu0 = ((const f4*)(feat_src + (size_t)sNxt * CHW))[i4a];
    f4 pu1 = ((const f4*)(feat_src + (size_t)sNxt * CHW))[i4b];
    f4 pv0 = ((const f4*)(feat_dst + (size_t)dNxt * CHW))[i4a];
    f4 pv1 = ((const f4*)(feat_dst + (size_t)dNxt * CHW))[i4b];
    __syncthreads();   // tile zero + weights done
    {
        f4 ea = pu0 + pv0;
        f4 eb = pu1 + pv1;
        *(f4*)&s_ef[sa] = ea;
        *(f4*)&s_ef[sb] = eb;
    }
    __syncthreads();

    for (int k = 0; k < EPB; ++k) {
        const int e    = e0 + k;
        const int sCur = sNxt, dCur = dNxt;

        // prefetch next edge's features (in flight during compute)
        if (k + 1 < EPB) {
            sNxt = src_idx[e + 1];
            dNxt = dst_idx[e + 1];
            const f4* up = (const f4*)(feat_src + (size_t)sNxt * CHW);
            const f4* vp = (const f4*)(feat_dst + (size_t)dNxt * CHW);
            pu0 = up[i4a]; pu1 = up[i4b];
            pv0 = vp[i4a]; pv1 = vp[i4b];
        }

        // ---- conv: 8 outputs (2 rows x 4 cols) for channel co ----
        float wh[8];
        #pragma unroll
        for (int i = 0; i < 8; ++i) wh[i] = bco;

        #pragma unroll
        for (int ci = 0; ci < NC; ++ci) {
            float win[4][6];
            #pragma unroll
            for (int row = 0; row < 4; ++row) {
                const int base = wbase + ci * PLANE + row * ROWW;
                f4 mid = *(const f4*)&s_ef[base + 4];
                win[row][0] = s_ef[base + 3];
                win[row][1] = mid.x;
                win[row][2] = mid.y;
                win[row][3] = mid.z;
                win[row][4] = mid.w;
                win[row][5] = s_ef[base + 8];
            }
            float w9[9];
            #pragma unroll
            for (int t = 0; t < 9; ++t) w9[t] = s_w[wgt0 + ci * 72 + t];
            #pragma unroll
            for (int dy = 0; dy < 2; ++dy)
                #pragma unroll
                for (int ky = 0; ky < 3; ++ky)
                    #pragma unroll
                    for (int dx = 0; dx < 4; ++dx)
                        #pragma unroll
                        for (int kx = 0; kx < 3; ++kx)
                            wh[dy * 4 + dx] = fmaf(win[dy + ky][dx + kx],
                                                   w9[ky * 3 + kx], wh[dy * 4 + dx]);
        }

        // ---- epilogue: Wh nt stores + atomic mean into h ----
        {
            float* whp = Wh_out + (size_t)e * CHW;
            f4 wa = {wh[0], wh[1], wh[2], wh[3]};
            f4 wb = {wh[4], wh[5], wh[6], wh[7]};
            __builtin_nontemporal_store(wa, (f4*)&whp[offA]);
            __builtin_nontemporal_store(wb, (f4*)&whp[offB]);
            const float inv = 1.0f / (float)cnt[dCur];
            const float* up = feat_src + (size_t)sCur * CHW;
            f4 uA = *(const f4*)&up[offA];
            f4 uB = *(const f4*)&up[offB];
            float* hp = h_acc + (size_t)dCur * CHW;
            atomicAdd(&hp[offA + 0], (uA.x + wa.x) * inv);
            atomicAdd(&hp[offA + 1], (uA.y + wa.y) * inv);
            atomicAdd(&hp[offA + 2], (uA.z + wa.z) * inv);
            atomicAdd(&hp[offA + 3], (uA.w + wa.w) * inv);
            atomicAdd(&hp[offB + 0], (uB.x + wb.x) * inv);
            atomicAdd(&hp[offB + 1], (uB.y + wb.y) * inv);
            atomicAdd(&hp[offB + 2], (uB.z + wb.z) * inv);
            atomicAdd(&hp[offB + 3], (uB.w + wb.w) * inv);
        }

        // ---- stage next edge's tile ----
        if (k + 1 < EPB) {
            __syncthreads();   // all waves done reading current tile
            f4 ea = pu0 + pv0;
            f4 eb = pu1 + pv1;
            *(f4*)&s_ef[sa] = ea;
            *(f4*)&s_ef[sb] = eb;
            __syncthreads();   // writes visible
        }
    }
}

extern "C" void kernel_launch(void* const* d_in, const int* in_sizes, int n_in,
                              void* d_out, int out_size, void* d_ws, size_t ws_size,
                              hipStream_t stream) {
    const float* feat_a = (const float*)d_in[0];
    const float* feat_b = (const float*)d_in[1];
    const float* W_e1   = (const float*)d_in[2];
    const float* b_e1   = (const float*)d_in[3];
    const float* W_e2   = (const float*)d_in[4];
    const float* b_e2   = (const float*)d_in[5];
    const int*   src_e1 = (const int*)d_in[6];
    const int*   dst_e1 = (const int*)d_in[7];
    const int*   src_e2 = (const int*)d_in[8];
    const int*   dst_e2 = (const int*)d_in[9];

    float* out = (float*)d_out;
    float* h_a = out;                                  // [NA, 2048]
    float* h_b = out + (size_t)NA * CHW;               // [NB, 2048]
    float* Wh1 = out + (size_t)(NA + NB) * CHW;        // [E, 2048]
    float* Wh2 = Wh1 + (size_t)NE * CHW;               // [E, 2048]

    int* cnt_a = (int*)d_ws;        // [NA] in-degree under etype2 (dst in a)
    int* cnt_b = cnt_a + NA;        // [NB] in-degree under etype1 (dst in b)

    // zero h accumulators + counts
    size_t nh4 = (size_t)(NA + NB) * CHW / 4;
    size_t nc4 = (size_t)(NA + NB) / 4;
    zero_kernel<<<2048, 256, 0, stream>>>((f4*)h_a, nh4, (i4v*)d_ws, nc4);

    // in-degree histograms
    hist_kernel<<<(NE + 255) / 256, 256, 0, stream>>>(dst_e1, cnt_b, NE);
    hist_kernel<<<(NE + 255) / 256, 256, 0, stream>>>(dst_e2, cnt_a, NE);

    // etype e1: a -> b   (writes Wh1, accumulates mean into h_b)
    conv_kernel<<<NBLK, 256, 0, stream>>>(feat_a, feat_b, W_e1, b_e1,
                                          src_e1, dst_e1, cnt_b, Wh1, h_b);
    // etype e2: b -> a   (writes Wh2, accumulates mean into h_a)
    conv_kernel<<<NBLK, 256, 0, stream>>>(feat_b, feat_a, W_e2, b_e2,
                                          src_e2, dst_e2, cnt_a, Wh2, h_a);
}

// Round 8
// 1359.014 us; speedup vs baseline: 1.3618x; 1.2641x over previous
//
#include <hip/hip_runtime.h>
#include <hip/hip_bf16.h>

#define NA 8192
#define NB 8192
#define NE 32768
#define NC 8
#define CHW 2048        // 8*16*16
#define ROWW 20         // words per padded row: cols 0-3 zero pad, 4-19 data
#define PLANE (18 * ROWW)           // rows 0 and 17 are zero pads
#define TILEW (NC * PLANE + 4)      // 2884 (div by 4); +4 catches last right-halo read

typedef float f4 __attribute__((ext_vector_type(4)));

// ---------------- CSR build (tiny kernels) ----------------
__global__ __launch_bounds__(256) void zero_two_kernel(int* a, int* b, int n) {
    int i = blockIdx.x * 256 + threadIdx.x;
    if (i < n) { a[i] = 0; b[i] = 0; }
}

__global__ __launch_bounds__(256) void hist_kernel(
    const int* __restrict__ dst, int* __restrict__ cnt, int n) {
    int i = blockIdx.x * 256 + threadIdx.x;
    if (i < n) atomicAdd(&cnt[dst[i]], 1);
}

// single-block exclusive scan over n=8192 counts -> row[0..n], cursor copy
__global__ __launch_bounds__(256) void scan_kernel(
    const int* __restrict__ cnt, int* __restrict__ row, int* __restrict__ cur, int n) {
    __shared__ int part[256];
    const int t = threadIdx.x;
    const int chunk = (n + 255) / 256;
    const int base = t * chunk;
    int sum = 0;
    for (int j = 0; j < chunk; ++j) { int idx = base + j; if (idx < n) sum += cnt[idx]; }
    part[t] = sum;
    __syncthreads();
    if (t == 0) {
        int run = 0;
        for (int i = 0; i < 256; ++i) { int tmp = part[i]; part[i] = run; run += tmp; }
    }
    __syncthreads();
    int run = part[t];
    for (int j = 0; j < chunk; ++j) {
        int idx = base + j;
        if (idx < n) { row[idx] = run; cur[idx] = run; run += cnt[idx]; }
    }
    if (t == 255) row[n] = run;
}

__global__ __launch_bounds__(256) void scatter_kernel(
    const int* __restrict__ dst, int* __restrict__ cur, int* __restrict__ perm, int n) {
    int i = blockIdx.x * 256 + threadIdx.x;
    if (i < n) { int p = atomicAdd(&cur[dst[i]], 1); perm[p] = i; }
}

// ---------------- Phase A: conv, one WAVE per edge, barrier-free ----------------
// Lane owns spatial row y = lane>>2, cols xg..xg+3 (xg=(lane&3)*4), ALL 8 co
// -> 32 accumulators. Windows from wave-private zero-padded LDS tile
// (9 LDS instrs per ci). Weights: lane l preloads w[co=l>>3][ci=l&7][0..8]
// into 9 VGPRs; conv reads them via readlane (VALU broadcast, no LDS/VMEM).
__global__ __launch_bounds__(128) void conv_kernel(
    const float* __restrict__ feat_src,   // [Nsrc, 2048]
    const float* __restrict__ feat_dst,   // [Ndst, 2048]
    const float* __restrict__ Wc,         // [8,8,3,3] OIHW
    const float* __restrict__ bias,       // [8]
    const int*   __restrict__ src_idx,    // [E]
    const int*   __restrict__ dst_idx,    // [E]
    float*       __restrict__ Wh_out)     // [E, 2048]
{
    __shared__ float lds[2 * TILEW];      // 23.1 KB -> ~6 blocks/CU (12 waves)
    const int tid  = threadIdx.x;
    const int lane = tid & 63;
    const int widx = tid >> 6;
    float* tp = &lds[widx * TILEW];

    const int e = blockIdx.x * 2 + widx;  // grid = NE/2, always valid
    const int s = src_idx[e];
    const int d = dst_idx[e];

    // zero wave-private tile (wave program order suffices; no barrier)
    #pragma unroll
    for (int k = 0; k < 12; ++k) {
        int i4 = lane + 64 * k;
        if (i4 < TILEW / 4) { f4 z = {0.f, 0.f, 0.f, 0.f}; *(f4*)&tp[i4 * 4] = z; }
    }

    // per-lane weight block: lane l holds pair p=l -> (co=l>>3, ci=l&7), 9 taps
    float wreg[9];
    #pragma unroll
    for (int j = 0; j < 9; ++j) wreg[j] = Wc[lane * 9 + j];
    const float breg = bias[lane & 7];

    // stage ef = u + v into tile interior (rows 1..16, cols 4..19)
    {
        const f4* up = (const f4*)(feat_src + (size_t)s * CHW);
        const f4* vp = (const f4*)(feat_dst + (size_t)d * CHW);
        #pragma unroll
        for (int k = 0; k < 8; ++k) {
            int i4 = lane + 64 * k;
            f4 ef = up[i4] + vp[i4];
            int c  = i4 >> 6;
            int yy = (i4 >> 2) & 15;
            int xx = (i4 & 3) * 4;
            *(f4*)&tp[c * PLANE + (yy + 1) * ROWW + xx + 4] = ef;
        }
    }

    const int y  = lane >> 2;             // 0..15
    const int xg = (lane & 3) * 4;        // 0,4,8,12

    float wh[NC][4];
    #pragma unroll
    for (int co = 0; co < NC; ++co) {
        float b = __uint_as_float(__builtin_amdgcn_readlane(__float_as_uint(breg), co));
        #pragma unroll
        for (int i = 0; i < 4; ++i) wh[co][i] = b;
    }

    #pragma unroll
    for (int ci = 0; ci < NC; ++ci) {
        // 3x6 window: padded rows y..y+2, absolute cols xg+3 .. xg+8
        const int base = ci * PLANE + y * ROWW + xg + 4;
        float win[3][6];
        #pragma unroll
        for (int r = 0; r < 3; ++r) {
            f4 mid = *(const f4*)&tp[base + r * ROWW];
            win[r][0] = tp[base + r * ROWW - 1];
            win[r][1] = mid.x; win[r][2] = mid.y; win[r][3] = mid.z; win[r][4] = mid.w;
            win[r][5] = tp[base + r * ROWW + 4];
        }
        #pragma unroll
        for (int co = 0; co < NC; ++co) {
            const int p = co * NC + ci;   // source lane holding these 9 weights
            float w[9];
            #pragma unroll
            for (int j = 0; j < 9; ++j)
                w[j] = __uint_as_float(__builtin_amdgcn_readlane(__float_as_uint(wreg[j]), p));
            #pragma unroll
            for (int r = 0; r < 3; ++r)
                #pragma unroll
                for (int i = 0; i < 4; ++i)
                    #pragma unroll
                    for (int kx = 0; kx < 3; ++kx)
                        wh[co][i] = fmaf(win[r][i + kx], w[r * 3 + kx], wh[co][i]);
        }
    }

    // epilogue: nontemporal Wh stores (streamed; keep L3 for feats)
    float* whp = Wh_out + (size_t)e * CHW;
    #pragma unroll
    for (int co = 0; co < NC; ++co) {
        f4 w4 = {wh[co][0], wh[co][1], wh[co][2], wh[co][3]};
        __builtin_nontemporal_store(w4, (f4*)&whp[co * 256 + y * 16 + xg]);
    }
}

// ---------------- Phase B: segment mean, one WAVE per dst node ----------------
__global__ __launch_bounds__(256) void mean_kernel(
    const float* __restrict__ Wh,         // [E, 2048]
    const float* __restrict__ feat_src,   // [Nsrc, 2048]
    const int*   __restrict__ src_idx,    // [E]
    const int*   __restrict__ row,        // [Ndst+1]
    const int*   __restrict__ perm,       // [E] edge ids grouped by dst
    float*       __restrict__ h_out,      // [Ndst, 2048]
    int n_nodes)
{
    const int tid  = threadIdx.x;
    const int lane = tid & 63;
    const int n    = blockIdx.x * 4 + (tid >> 6);
    if (n >= n_nodes) return;
    const int beg = row[n], end = row[n + 1];

    f4 acc[8];
    #pragma unroll
    for (int k = 0; k < 8; ++k) { f4 z = {0.f, 0.f, 0.f, 0.f}; acc[k] = z; }

    for (int i = beg; i < end; ++i) {
        const int e = perm[i];
        const int s = src_idx[e];
        const f4* wp = (const f4*)(Wh + (size_t)e * CHW);
        const f4* up = (const f4*)(feat_src + (size_t)s * CHW);
        #pragma unroll
        for (int k = 0; k < 8; ++k) {
            int i4 = lane + 64 * k;
            f4 a = __builtin_nontemporal_load(&wp[i4]);   // Wh read once
            acc[k] += a + up[i4];                          // u cached (L3)
        }
    }

    const float inv = end > beg ? 1.0f / (float)(end - beg) : 0.0f;
    float* hp = h_out + (size_t)n * CHW;
    #pragma unroll
    for (int k = 0; k < 8; ++k) {
        f4 o = acc[k] * inv;
        __builtin_nontemporal_store(o, (f4*)&hp[(lane + 64 * k) * 4]);
    }
}

extern "C" void kernel_launch(void* const* d_in, const int* in_sizes, int n_in,
                              void* d_out, int out_size, void* d_ws, size_t ws_size,
                              hipStream_t stream) {
    const float* feat_a = (const float*)d_in[0];
    const float* feat_b = (const float*)d_in[1];
    const float* W_e1   = (const float*)d_in[2];
    const float* b_e1   = (const float*)d_in[3];
    const float* W_e2   = (const float*)d_in[4];
    const float* b_e2   = (const float*)d_in[5];
    const int*   src_e1 = (const int*)d_in[6];
    const int*   dst_e1 = (const int*)d_in[7];
    const int*   src_e2 = (const int*)d_in[8];
    const int*   dst_e2 = (const int*)d_in[9];

    float* out = (float*)d_out;
    float* h_a = out;                                  // [NA, 2048]
    float* h_b = out + (size_t)NA * CHW;               // [NB, 2048]
    float* Wh1 = out + (size_t)(NA + NB) * CHW;        // [E, 2048]
    float* Wh2 = Wh1 + (size_t)NE * CHW;               // [E, 2048]

    // workspace: CSR for both etypes (~460 KB of the 2 GB ws)
    int* ws    = (int*)d_ws;
    int* cnt1  = ws;                  // [NB]
    int* row1  = cnt1 + NB;           // [NB+1]
    int* cur1  = row1 + NB + 1;       // [NB]
    int* perm1 = cur1 + NB;           // [NE]
    int* cnt2  = perm1 + NE;          // [NA]
    int* row2  = cnt2 + NA;           // [NA+1]
    int* cur2  = row2 + NA + 1;       // [NA]
    int* perm2 = cur2 + NA;           // [NE]

    // CSR build
    zero_two_kernel<<<(NB + 255) / 256, 256, 0, stream>>>(cnt1, cnt2, NB);
    hist_kernel<<<(NE + 255) / 256, 256, 0, stream>>>(dst_e1, cnt1, NE);
    hist_kernel<<<(NE + 255) / 256, 256, 0, stream>>>(dst_e2, cnt2, NE);
    scan_kernel<<<1, 256, 0, stream>>>(cnt1, row1, cur1, NB);
    scan_kernel<<<1, 256, 0, stream>>>(cnt2, row2, cur2, NA);
    scatter_kernel<<<(NE + 255) / 256, 256, 0, stream>>>(dst_e1, cur1, perm1, NE);
    scatter_kernel<<<(NE + 255) / 256, 256, 0, stream>>>(dst_e2, cur2, perm2, NE);

    // Phase A: conv (wave per edge)
    conv_kernel<<<NE / 2, 128, 0, stream>>>(feat_a, feat_b, W_e1, b_e1,
                                            src_e1, dst_e1, Wh1);
    conv_kernel<<<NE / 2, 128, 0, stream>>>(feat_b, feat_a, W_e2, b_e2,
                                            src_e2, dst_e2, Wh2);

    // Phase B: segment mean (wave per node); h fully overwritten -> no zeroing
    mean_kernel<<<NB / 4, 256, 0, stream>>>(Wh1, feat_a, src_e1, row1, perm1, h_b, NB);
    mean_kernel<<<NA / 4, 256, 0, stream>>>(Wh2, feat_b, src_e2, row2, perm2, h_a, NA);
}

// Round 9
// 481.024 us; speedup vs baseline: 3.8473x; 2.8253x over previous
//
#include <hip/hip_runtime.h>
#include <hip/hip_bf16.h>

#define NA 8192
#define NB 8192
#define NE 32768
#define NC 8
#define CHW 2048        // 8*16*16

typedef float  f4     __attribute__((ext_vector_type(4)));
typedef float  f32x4  __attribute__((ext_vector_type(4)));
typedef short  short8 __attribute__((ext_vector_type(8)));

// conv LDS tile: [18 rows][18 cols][8 ci] bf16; 16 B per (row,col) cell.
// Row 0/17, col 0/17 are the zero halo (SAME padding), ci is innermost so a
// B-fragment (8 ci at one spatial point) is ONE aligned ds_read_b128.
#define CELLS (18 * 18)          // 324 cells
#define TILE_US (CELLS * 8)      // 2592 ushort = 5184 B per wave tile

static __device__ __forceinline__ unsigned short f2bf(float f) {
    unsigned u = __float_as_uint(f);
    u = (u + 0x7FFFu + ((u >> 16) & 1u)) >> 16;   // RNE bf16
    return (unsigned short)u;
}

// ---------------- CSR build (tiny kernels) ----------------
__global__ __launch_bounds__(256) void zero_two_kernel(int* a, int* b, int n) {
    int i = blockIdx.x * 256 + threadIdx.x;
    if (i < n) { a[i] = 0; b[i] = 0; }
}

__global__ __launch_bounds__(256) void hist_kernel(
    const int* __restrict__ dst, int* __restrict__ cnt, int n) {
    int i = blockIdx.x * 256 + threadIdx.x;
    if (i < n) atomicAdd(&cnt[dst[i]], 1);
}

__global__ __launch_bounds__(256) void scan_kernel(
    const int* __restrict__ cnt, int* __restrict__ row, int* __restrict__ cur, int n) {
    __shared__ int part[256];
    const int t = threadIdx.x;
    const int chunk = (n + 255) / 256;
    const int base = t * chunk;
    int sum = 0;
    for (int j = 0; j < chunk; ++j) { int idx = base + j; if (idx < n) sum += cnt[idx]; }
    part[t] = sum;
    __syncthreads();
    if (t == 0) {
        int run = 0;
        for (int i = 0; i < 256; ++i) { int tmp = part[i]; part[i] = run; run += tmp; }
    }
    __syncthreads();
    int run = part[t];
    for (int j = 0; j < chunk; ++j) {
        int idx = base + j;
        if (idx < n) { row[idx] = run; cur[idx] = run; run += cnt[idx]; }
    }
    if (t == 255) row[n] = run;
}

__global__ __launch_bounds__(256) void scatter_kernel(
    const int* __restrict__ dst, int* __restrict__ cur, int* __restrict__ perm, int n) {
    int i = blockIdx.x * 256 + threadIdx.x;
    if (i < n) { int p = atomicAdd(&cur[dst[i]], 1); perm[p] = i; }
}

// ---------------- Phase A: conv via bf16 MFMA, one WAVE per edge ----------------
// GEMM view per edge: D[16][16] per spatial row-pair, M=(s,co), N=x, K=96:
//   k = (pair=(dy'∈4 x dx∈3)) * 8 + ci, split into 3 MFMA k-steps of 32.
//   A[(s,co)][k] = W[co][ci][dy'-s+1][dx] (0 if ky out of range) -> edge-invariant.
//   B[k][x]      = ef[ci][2y+dy'][x+dx-1] -> one ds_read_b128 per (lane,kstep).
// 24 MFMA per edge (75% useful), no barriers (wave-private LDS tiles).
__global__ __launch_bounds__(256, 4) void conv_kernel(
    const float* __restrict__ feat_src,   // [Nsrc, 2048]
    const float* __restrict__ feat_dst,   // [Ndst, 2048]
    const float* __restrict__ Wc,         // [8,8,3,3] OIHW
    const float* __restrict__ bias,       // [8]
    const int*   __restrict__ src_idx,    // [E]
    const int*   __restrict__ dst_idx,    // [E]
    float*       __restrict__ Wh_out)     // [E, 2048]
{
    __shared__ unsigned short lds[4 * TILE_US];   // 20.7 KB / block
    const int tid  = threadIdx.x;
    const int lane = tid & 63;
    const int widx = tid >> 6;
    unsigned short* tp = &lds[widx * TILE_US];

    const int e = blockIdx.x * 4 + widx;          // grid = NE/4, always valid
    const int s = src_idx[e];
    const int d = dst_idx[e];

    const int g = lane >> 4;      // lane group 0..3 (k-chunk)
    const int x = lane & 15;      // A-row index m / B-col index x / D-col

    // ---- A fragments (weights, edge-independent; 12 VGPRs) ----
    short8 aF[3];
    #pragma unroll
    for (int K = 0; K < 3; ++K) {
        #pragma unroll
        for (int j = 0; j < 8; ++j) {
            const int k    = K * 32 + g * 8 + j;
            const int pair = k >> 3;              // K*4 + g
            const int dy   = pair / 3 - 1;        // -1..2
            const int dx   = pair % 3;            // 0..2
            const int ci   = k & 7;
            const int m    = x;                   // A row
            const int sd   = m >> 3;              // output-row parity
            const int co   = m & 7;
            const int ky   = dy - sd + 1;
            float w = (ky >= 0 && ky <= 2) ? Wc[((co * 8 + ci) * 3 + ky) * 3 + dx] : 0.0f;
            aF[K][j] = (short)f2bf(w);
        }
    }
    // B cell offsets per k-step (add 36*y per row-pair): (dy+1)*18 + (x+dx)
    int boff[3];
    #pragma unroll
    for (int K = 0; K < 3; ++K) {
        const int pair = K * 4 + g;
        const int dy   = pair / 3 - 1;
        const int dx   = pair % 3;
        boff[K] = (dy + 1) * 18 + (x + dx);
    }
    // bias into the accumulator init (D row m = g*4 + j)
    f32x4 cb;
    #pragma unroll
    for (int j = 0; j < 4; ++j) cb[j] = bias[(g * 4 + j) & 7];

    // ---- zero tile (halo) ----
    const f4 z4 = {0.f, 0.f, 0.f, 0.f};
    #pragma unroll
    for (int i = 0; i < 6; ++i) {
        int c = lane + 64 * i;
        if (c < CELLS) *(f4*)&tp[c * 8] = z4;
    }

    // ---- stage ef = bf16(u+v): lane owns cell rows (sy+1), cols sx+1..sx+4 ----
    {
        const int sy = lane >> 2;          // 0..15
        const int sx = (lane & 3) * 4;     // 0,4,8,12
        const f4* up = (const f4*)(feat_src + (size_t)s * CHW);
        const f4* vp = (const f4*)(feat_dst + (size_t)d * CHW);
        short8 pk[4];
        #pragma unroll
        for (int ci = 0; ci < 8; ++ci) {
            const int i4 = lane + 64 * ci;         // i4>>6 == ci for lane<64
            f4 ef = up[i4] + vp[i4];
            pk[0][ci] = (short)f2bf(ef.x);
            pk[1][ci] = (short)f2bf(ef.y);
            pk[2][ci] = (short)f2bf(ef.z);
            pk[3][ci] = (short)f2bf(ef.w);
        }
        #pragma unroll
        for (int m = 0; m < 4; ++m) {
            const int cell = (sy + 1) * 18 + (sx + 1 + m);
            *(short8*)&tp[cell * 8] = pk[m];       // ds_write_b128
        }
    }
    // wave-private tile: no __syncthreads needed (compiler orders via lgkmcnt)

    // ---- 8 row-pair MFMA triplets + nontemporal stores ----
    float* whp = Wh_out + (size_t)e * CHW;
    #pragma unroll
    for (int y = 0; y < 8; ++y) {
        f32x4 acc = cb;
        #pragma unroll
        for (int K = 0; K < 3; ++K) {
            short8 b = *(const short8*)&tp[(36 * y + boff[K]) * 8];  // ds_read_b128
            acc = __builtin_amdgcn_mfma_f32_16x16x32_bf16(aF[K], b, acc, 0, 0, 0);
        }
        #pragma unroll
        for (int j = 0; j < 4; ++j) {
            const int m  = g * 4 + j;              // D row = (lane>>4)*4 + reg
            const int sd = m >> 3, co = m & 7;
            __builtin_nontemporal_store(acc[j], &whp[co * 256 + (2 * y + sd) * 16 + x]);
        }
    }
}

// ---------------- Phase B: segment mean, one WAVE per dst node ----------------
__global__ __launch_bounds__(256) void mean_kernel(
    const float* __restrict__ Wh,         // [E, 2048]
    const float* __restrict__ feat_src,   // [Nsrc, 2048]
    const int*   __restrict__ src_idx,    // [E]
    const int*   __restrict__ row,        // [Ndst+1]
    const int*   __restrict__ perm,       // [E] edge ids grouped by dst
    float*       __restrict__ h_out,      // [Ndst, 2048]
    int n_nodes)
{
    const int tid  = threadIdx.x;
    const int lane = tid & 63;
    const int n    = blockIdx.x * 4 + (tid >> 6);
    if (n >= n_nodes) return;
    const int beg = row[n], end = row[n + 1];

    f4 acc[8];
    #pragma unroll
    for (int k = 0; k < 8; ++k) { f4 z = {0.f, 0.f, 0.f, 0.f}; acc[k] = z; }

    for (int i = beg; i < end; ++i) {
        const int e = perm[i];
        const int sidx = src_idx[e];
        const f4* wp = (const f4*)(Wh + (size_t)e * CHW);
        const f4* up = (const f4*)(feat_src + (size_t)sidx * CHW);
        #pragma unroll
        for (int k = 0; k < 8; ++k) {
            int i4 = lane + 64 * k;
            f4 a = __builtin_nontemporal_load(&wp[i4]);   // Wh read once
            acc[k] += a + up[i4];                          // u served by L2/L3
        }
    }

    const float inv = end > beg ? 1.0f / (float)(end - beg) : 0.0f;
    float* hp = h_out + (size_t)n * CHW;
    #pragma unroll
    for (int k = 0; k < 8; ++k) {
        f4 o = acc[k] * inv;
        __builtin_nontemporal_store(o, (f4*)&hp[(lane + 64 * k) * 4]);
    }
}

extern "C" void kernel_launch(void* const* d_in, const int* in_sizes, int n_in,
                              void* d_out, int out_size, void* d_ws, size_t ws_size,
                              hipStream_t stream) {
    const float* feat_a = (const float*)d_in[0];
    const float* feat_b = (const float*)d_in[1];
    const float* W_e1   = (const float*)d_in[2];
    const float* b_e1   = (const float*)d_in[3];
    const float* W_e2   = (const float*)d_in[4];
    const float* b_e2   = (const float*)d_in[5];
    const int*   src_e1 = (const int*)d_in[6];
    const int*   dst_e1 = (const int*)d_in[7];
    const int*   src_e2 = (const int*)d_in[8];
    const int*   dst_e2 = (const int*)d_in[9];

    float* out = (float*)d_out;
    float* h_a = out;                                  // [NA, 2048]
    float* h_b = out + (size_t)NA * CHW;               // [NB, 2048]
    float* Wh1 = out + (size_t)(NA + NB) * CHW;        // [E, 2048]
    float* Wh2 = Wh1 + (size_t)NE * CHW;               // [E, 2048]

    // workspace: CSR for both etypes
    int* ws    = (int*)d_ws;
    int* cnt1  = ws;                  // [NB]
    int* row1  = cnt1 + NB;           // [NB+1]
    int* cur1  = row1 + NB + 1;       // [NB]
    int* perm1 = cur1 + NB;           // [NE]
    int* cnt2  = perm1 + NE;          // [NA]
    int* row2  = cnt2 + NA;           // [NA+1]
    int* cur2  = row2 + NA + 1;       // [NA]
    int* perm2 = cur2 + NA;           // [NE]

    // CSR build
    zero_two_kernel<<<(NB + 255) / 256, 256, 0, stream>>>(cnt1, cnt2, NB);
    hist_kernel<<<(NE + 255) / 256, 256, 0, stream>>>(dst_e1, cnt1, NE);
    hist_kernel<<<(NE + 255) / 256, 256, 0, stream>>>(dst_e2, cnt2, NE);
    scan_kernel<<<1, 256, 0, stream>>>(cnt1, row1, cur1, NB);
    scan_kernel<<<1, 256, 0, stream>>>(cnt2, row2, cur2, NA);
    scatter_kernel<<<(NE + 255) / 256, 256, 0, stream>>>(dst_e1, cur1, perm1, NE);
    scatter_kernel<<<(NE + 255) / 256, 256, 0, stream>>>(dst_e2, cur2, perm2, NE);

    // Phase A: conv (MFMA, wave per edge)
    conv_kernel<<<NE / 4, 256, 0, stream>>>(feat_a, feat_b, W_e1, b_e1,
                                            src_e1, dst_e1, Wh1);
    conv_kernel<<<NE / 4, 256, 0, stream>>>(feat_b, feat_a, W_e2, b_e2,
                                            src_e2, dst_e2, Wh2);

    // Phase B: segment mean (wave per node); h fully overwritten -> no zeroing
    mean_kernel<<<NB / 4, 256, 0, stream>>>(Wh1, feat_a, src_e1, row1, perm1, h_b, NB);
    mean_kernel<<<NA / 4, 256, 0, stream>>>(Wh2, feat_b, src_e2, row2, perm2, h_a, NA);
}